// Round 8
// baseline (730.048 us; speedup 1.0000x reference)
//
#include <hip/hip_runtime.h>
#include <hip/hip_bf16.h>
#include <math.h>

#define NT 384   // turns
#define TL 384   // per-turn seq len
#define HD 768   // hidden
#define DD 128   // qk proj dim
#define PT_T 86016          // packed P elems per t: 64*64*Sum_{it<6}(it+1)
// packed P layout per t: tile it64 at 2048*it64*(it64+1); chunk32 jc at +jc*2048;
// elem (i_local 0..63, jo 0..31): + i_local*32 + jo.

typedef __attribute__((ext_vector_type(8))) short bf16x8;
typedef __attribute__((ext_vector_type(8))) unsigned short u16x8;
typedef __attribute__((ext_vector_type(4))) float f32x4;

__device__ __forceinline__ unsigned short f2b(float f) {
    union { float f; unsigned int u; } v; v.f = f;
    unsigned int r = v.u + 0x7FFFu + ((v.u >> 16) & 1u);   // RNE
    return (unsigned short)(r >> 16);
}

// ---------------------------------------------------------------------------
// kw_prep: Wt[n][k] = bf16(n<128 ? Wq[k][n] : Wk[k][n-128]); [256][768]
// ---------------------------------------------------------------------------
__global__ __launch_bounds__(256) void kw_prep(
    const float* __restrict__ Wq, const float* __restrict__ Wk,
    unsigned short* __restrict__ Wt)
{
    const int idx = blockIdx.x * 256 + threadIdx.x;     // 0 .. 196607
    const int k = idx >> 8, n = idx & 255;
    const float v = (n < DD) ? Wq[(size_t)k * DD + n] : Wk[(size_t)k * DD + (n - DD)];
    Wt[(size_t)n * HD + k] = f2b(v);
}

// ---------------------------------------------------------------------------
// k_proj: MFMA GEMM  C[147456][256] = x[147456][768] @ (Wq|Wk)[768][256]
// Outputs in [t][row][d] layout: qg/kg[((t*NT)+i)*DD + d].
// ---------------------------------------------------------------------------
__global__ __launch_bounds__(256, 3) void k_proj(
    const float* __restrict__ x, const unsigned short* __restrict__ Wt,
    const float* __restrict__ bq, const float* __restrict__ bk,
    unsigned short* __restrict__ qg, unsigned short* __restrict__ kg)
{
    __shared__ unsigned short As[64 * 64];   // [m][k] bf16, 16B-chunk XOR swizzle
    const int tid = threadIdx.x;
    const int lane = tid & 63;
    const int w = tid >> 6;
    const int row0 = blockIdx.x * 64;
    const int n0w = w * 64;
    const int lr = lane & 15;
    const int lg = lane >> 4;

    f32x4 acc[4][4];
    #pragma unroll
    for (int m = 0; m < 4; ++m)
        #pragma unroll
        for (int n = 0; n < 4; ++n) acc[m][n] = (f32x4){0.f, 0.f, 0.f, 0.f};

    const int sm = tid >> 2;           // staging row 0..63
    const int sc0 = (tid & 3) * 2;     // staging 16B-chunk pair

    for (int k0 = 0; k0 < HD; k0 += 64) {
        __syncthreads();
        {   // stage A tile [64 m][64 k] as bf16, swizzled
            const float* xp = x + (size_t)(row0 + sm) * HD + k0 + (tid & 3) * 16;
            u16x8 v0, v1;
            #pragma unroll
            for (int u4 = 0; u4 < 2; ++u4) {
                float4 f = *(const float4*)(xp + u4 * 4);
                v0[u4*4+0] = f2b(f.x); v0[u4*4+1] = f2b(f.y);
                v0[u4*4+2] = f2b(f.z); v0[u4*4+3] = f2b(f.w);
            }
            #pragma unroll
            for (int u4 = 0; u4 < 2; ++u4) {
                float4 f = *(const float4*)(xp + 8 + u4 * 4);
                v1[u4*4+0] = f2b(f.x); v1[u4*4+1] = f2b(f.y);
                v1[u4*4+2] = f2b(f.z); v1[u4*4+3] = f2b(f.w);
            }
            *(u16x8*)&As[sm * 64 + ((sc0     ^ (sm & 7)) * 8)] = v0;
            *(u16x8*)&As[sm * 64 + (((sc0+1) ^ (sm & 7)) * 8)] = v1;
        }
        __syncthreads();
        #pragma unroll
        for (int kk = 0; kk < 2; ++kk) {
            bf16x8 a[4], b[4];
            #pragma unroll
            for (int m = 0; m < 4; ++m) {
                const int mi = m * 16 + lr;
                const int phys = (lg + kk * 4) ^ (mi & 7);
                a[m] = *(const bf16x8*)&As[mi * 64 + phys * 8];
            }
            #pragma unroll
            for (int n = 0; n < 4; ++n) {
                const int ncol = n0w + n * 16 + lr;
                b[n] = *(const bf16x8*)(Wt + (size_t)ncol * HD + k0 + kk * 32 + lg * 8);
            }
            #pragma unroll
            for (int m = 0; m < 4; ++m)
                #pragma unroll
                for (int n = 0; n < 4; ++n)
                    acc[m][n] = __builtin_amdgcn_mfma_f32_16x16x32_bf16(a[m], b[n], acc[m][n], 0, 0, 0);
        }
    }
    const float scale = 0.08838834764831845f;   // 1/sqrt(128), folded into q
    const int ib = row0 / TL;                   // turn index (constant per block)
    const int tb = row0 % TL;                   // base t within turn
    #pragma unroll
    for (int n = 0; n < 4; ++n) {
        const int ncol = n0w + n * 16 + lr;
        const bool isq = ncol < DD;
        const int d = isq ? ncol : ncol - DD;
        const float bias = isq ? bq[d] : bk[d];
        unsigned short* dst = isq ? qg : kg;
        #pragma unroll
        for (int m = 0; m < 4; ++m)
            #pragma unroll
            for (int r = 0; r < 4; ++r) {
                const int t = tb + m * 16 + lg * 4 + r;
                float v = acc[m][n][r] + bias;
                if (isq) v *= scale;
                dst[((size_t)t * NT + ib) * DD + d] = f2b(v);
            }
    }
}

// ---------------------------------------------------------------------------
// k_xt: xt5[t][j/32][h][j%32] = bf16(x[j][t][h]). Coalesced-write remap:
// thread = (joblk = tid&3, h_local = tid>>2); owns 8 j x 4 h. Each u16x8
// store covers jo joblk*8..+8 at fixed h -> a wave fills full 64B sectors.
// grid: (36 = jc*3+hb, 384 t).
// ---------------------------------------------------------------------------
__global__ __launch_bounds__(256, 4) void k_xt(
    const float* __restrict__ x, unsigned short* __restrict__ xt)
{
    const int tid = threadIdx.x;
    const int hb = blockIdx.x % 3;          // h-tile of 256
    const int jc = blockIdx.x / 3;          // j-chunk of 32
    const int t  = blockIdx.y;
    const int joblk   = tid & 3;            // jo base = joblk*8
    const int h_local = tid >> 2;           // 0..63 -> h = hb*256 + h_local*4
    const int hbase = hb * 256 + h_local * 4;

    float4 v[8];
    #pragma unroll
    for (int r = 0; r < 8; ++r) {
        const int j = jc * 32 + joblk * 8 + r;
        v[r] = *(const float4*)&x[((size_t)j * TL + t) * HD + hbase];
    }
    #pragma unroll
    for (int e = 0; e < 4; ++e) {
        u16x8 w;
        w[0] = f2b(v[0][e]); w[1] = f2b(v[1][e]);
        w[2] = f2b(v[2][e]); w[3] = f2b(v[3][e]);
        w[4] = f2b(v[4][e]); w[5] = f2b(v[5][e]);
        w[6] = f2b(v[6][e]); w[7] = f2b(v[7][e]);
        *(u16x8*)&xt[(((size_t)t * 12 + jc) * HD + hbase + e) * 32 + joblk * 8] = w;
    }
}

// ---------------------------------------------------------------------------
// k_qk: i-tile 64, 256 threads (4 waves). Per 64-j chunk: wave w owns
// j-slice w*16, computes S for all 4 m-tiles (16 MFMA / 4 loads),
// P = mask?exp(s):0 -> packed burst-layout Pt (bf16) + row-sum partials.
// ---------------------------------------------------------------------------
__global__ __launch_bounds__(256, 4) void k_qk(
    const unsigned short* __restrict__ qg, const unsigned short* __restrict__ kg,
    unsigned short* __restrict__ Pt, float* __restrict__ lpart)
{
    __shared__ float red[4][64];
    const int tid = threadIdx.x, lane = tid & 63, w = tid >> 6;
    const int lr = lane & 15, lg = lane >> 4;
    const int bid = blockIdx.x;
    const int lid = (bid & 7) * (2304 / 8) + (bid >> 3);   // XCD-chunk swizzle
    const int it = lid % 6, t = lid / 6;
    const int i0 = it * 64;
    unsigned short* ptile = Pt + (size_t)t * PT_T + 2048 * (size_t)(it * (it + 1));

    bf16x8 aq[4][4];
    #pragma unroll
    for (int m = 0; m < 4; ++m) {
        const unsigned short* qp = qg + ((size_t)t * NT + i0 + m * 16 + lr) * DD + lg * 8;
        #pragma unroll
        for (int kk = 0; kk < 4; ++kk) aq[m][kk] = *(const bf16x8*)(qp + kk * 32);
    }
    float psum[4][4];
    #pragma unroll
    for (int m = 0; m < 4; ++m)
        #pragma unroll
        for (int r = 0; r < 4; ++r) psum[m][r] = 0.f;

    for (int c = 0; c <= it; ++c) {
        const int j0 = c * 64;
        const unsigned short* kp = kg + ((size_t)t * NT + j0 + w * 16 + lr) * DD + lg * 8;
        bf16x8 bk8[4];
        #pragma unroll
        for (int kk = 0; kk < 4; ++kk) bk8[kk] = *(const bf16x8*)(kp + kk * 32);
        const int jg = j0 + w * 16 + lr;
        unsigned short* pst = ptile + (size_t)(c * 2 + (w >> 1)) * 2048 + (w & 1) * 16 + lr;
        #pragma unroll
        for (int m = 0; m < 4; ++m) {
            f32x4 s = (f32x4){0.f, 0.f, 0.f, 0.f};
            #pragma unroll
            for (int kk = 0; kk < 4; ++kk)
                s = __builtin_amdgcn_mfma_f32_16x16x32_bf16(aq[m][kk], bk8[kk], s, 0, 0, 0);
            #pragma unroll
            for (int r = 0; r < 4; ++r) {
                const int il = m * 16 + lg * 4 + r;
                const float wv = (jg <= i0 + il) ? __expf(s[r]) : 0.f;
                psum[m][r] += wv;
                pst[il * 32] = f2b(wv);
            }
        }
    }
    #pragma unroll
    for (int off = 1; off < 16; off <<= 1)
        #pragma unroll
        for (int m = 0; m < 4; ++m)
            #pragma unroll
            for (int r = 0; r < 4; ++r)
                psum[m][r] += __shfl_xor(psum[m][r], off);
    if (lr == 0) {
        #pragma unroll
        for (int m = 0; m < 4; ++m)
            #pragma unroll
            for (int r = 0; r < 4; ++r)
                red[w][m * 16 + lg * 4 + r] = psum[m][r];
    }
    __syncthreads();
    if (tid < 64)
        lpart[(size_t)(i0 + tid) * TL + t] = red[0][tid] + red[1][tid] + red[2][tid] + red[3][tid];
}

// ---------------------------------------------------------------------------
// k_lred: linv[i] = 1 / sum_t lpart[i][t]
// ---------------------------------------------------------------------------
__global__ __launch_bounds__(256) void k_lred(const float* __restrict__ lpart,
                                              float* __restrict__ linv)
{
    const int i = blockIdx.x;
    const int tid = threadIdx.x;
    float s = 0.f;
    for (int t = tid; t < TL; t += 256) s += lpart[(size_t)i * TL + t];
    #pragma unroll
    for (int off = 32; off >= 1; off >>= 1) s += __shfl_down(s, off);
    __shared__ float red[4];
    if ((tid & 63) == 0) red[tid >> 6] = s;
    __syncthreads();
    if (tid == 0) linv[i] = 1.f / (red[0] + red[1] + red[2] + red[3]);
}

// ---------------------------------------------------------------------------
// k_pv_g: pure GEMM, no LDS/barriers/exp. Block = (t, i-tile 32, h-256);
// 4 waves x h-64. acc[2][4] = 32 AGPR -> ~72 regs -> 6 waves/SIMD
// (__launch_bounds__(256,6)). Per 32-j chunk: 2 Pt A-frags + 4 xt B-frags
// (contiguous bursts) + 8 MFMA. Epilogue: out = acc*linv[i]; row-0
// fp32 passthrough folded in.
// ---------------------------------------------------------------------------
__global__ __launch_bounds__(256, 6) void k_pv_g(
    const unsigned short* __restrict__ Pt, const unsigned short* __restrict__ xt,
    const float* __restrict__ linv, const float* __restrict__ x,
    float* __restrict__ out)
{
    const int tid = threadIdx.x, lane = tid & 63, w = tid >> 6;
    const int lr = lane & 15, lg = lane >> 4;
    const int bid = blockIdx.x;             // 0 .. 13823
    const int lid = (bid & 7) * (13824 / 8) + (bid >> 3);
    const int hb  = lid % 3;
    const int rem = lid / 3;                // 0 .. 4607, t-contiguous per XCD
    const int it32 = rem % 12, t = rem / 12;
    const int i0 = it32 * 32;
    const int h0 = hb * 256 + w * 64;
    const int it64 = it32 >> 1;
    const int rowhalf = (it32 & 1) * 32;

    const unsigned short* pbase = Pt + (size_t)t * PT_T + 2048 * (size_t)(it64 * (it64 + 1))
                                + (size_t)(rowhalf + lr) * 32 + lg * 8;
    const unsigned short* xbase = xt + (((size_t)t * 12) * HD + h0 + lr) * 32 + lg * 8;

    f32x4 acc[2][4];
    #pragma unroll
    for (int m = 0; m < 2; ++m)
        #pragma unroll
        for (int n = 0; n < 4; ++n) acc[m][n] = (f32x4){0.f, 0.f, 0.f, 0.f};

    const int nq = it32 + 1;
    for (int q32 = 0; q32 < nq; ++q32) {
        bf16x8 pa[2];
        #pragma unroll
        for (int m = 0; m < 2; ++m)
            pa[m] = *(const bf16x8*)(pbase + (size_t)q32 * 2048 + m * 512);
        const unsigned short* xp = xbase + (size_t)q32 * (HD * 32);
        #pragma unroll
        for (int n = 0; n < 4; ++n) {
            const bf16x8 bx = *(const bf16x8*)(xp + n * 512);
            acc[0][n] = __builtin_amdgcn_mfma_f32_16x16x32_bf16(pa[0], bx, acc[0][n], 0, 0, 0);
            acc[1][n] = __builtin_amdgcn_mfma_f32_16x16x32_bf16(pa[1], bx, acc[1][n], 0, 0, 0);
        }
    }
    // ---- epilogue: normalize + single write; row-0 fp32 passthrough ----
    #pragma unroll
    for (int m = 0; m < 2; ++m)
        #pragma unroll
        for (int r = 0; r < 4; ++r) {
            const int gi = i0 + m * 16 + lg * 4 + r;
            float* op = out + ((size_t)gi * TL + t) * HD + h0 + lr;
            if (gi == 0) {
                const float* xp0 = x + (size_t)t * HD + h0 + lr;
                #pragma unroll
                for (int n = 0; n < 4; ++n) op[n * 16] = xp0[n * 16];
            } else {
                const float sc = linv[gi];
                #pragma unroll
                for (int n = 0; n < 4; ++n) op[n * 16] = acc[m][n][r] * sc;
            }
        }
}

// ---------------------------------------------------------------------------
// Fallback path (proven round-6): k_stats64 + k_pv3, used if ws too small.
// ---------------------------------------------------------------------------
__global__ __launch_bounds__(256, 4) void k_stats64(
    const unsigned short* __restrict__ qg, const unsigned short* __restrict__ kg,
    float* __restrict__ lpart)
{
    __shared__ float red[4][64];
    const int tid = threadIdx.x, lane = tid & 63, w = tid >> 6;
    const int lr = lane & 15, lg = lane >> 4;
    const int bid = blockIdx.x;
    const int lid = (bid & 7) * (2304 / 8) + (bid >> 3);
    const int it = lid % 6, t = lid / 6;
    const int i0 = it * 64;

    bf16x8 aq[4][4];
    #pragma unroll
    for (int m = 0; m < 4; ++m) {
        const unsigned short* qp = qg + ((size_t)t * NT + i0 + m * 16 + lr) * DD + lg * 8;
        #pragma unroll
        for (int kk = 0; kk < 4; ++kk) aq[m][kk] = *(const bf16x8*)(qp + kk * 32);
    }
    float psum[4][4];
    #pragma unroll
    for (int m = 0; m < 4; ++m)
        #pragma unroll
        for (int r = 0; r < 4; ++r) psum[m][r] = 0.f;

    for (int c = 0; c <= it; ++c) {
        const int j0 = c * 64;
        const unsigned short* kp = kg + ((size_t)t * NT + j0 + w * 16 + lr) * DD + lg * 8;
        bf16x8 bk8[4];
        #pragma unroll
        for (int kk = 0; kk < 4; ++kk) bk8[kk] = *(const bf16x8*)(kp + kk * 32);
        const int jg = j0 + w * 16 + lr;
        #pragma unroll
        for (int m = 0; m < 4; ++m) {
            f32x4 s = (f32x4){0.f, 0.f, 0.f, 0.f};
            #pragma unroll
            for (int kk = 0; kk < 4; ++kk)
                s = __builtin_amdgcn_mfma_f32_16x16x32_bf16(aq[m][kk], bk8[kk], s, 0, 0, 0);
            #pragma unroll
            for (int r = 0; r < 4; ++r) {
                const int ig = i0 + m * 16 + lg * 4 + r;
                psum[m][r] += (jg <= ig) ? __expf(s[r]) : 0.f;
            }
        }
    }
    #pragma unroll
    for (int off = 1; off < 16; off <<= 1)
        #pragma unroll
        for (int m = 0; m < 4; ++m)
            #pragma unroll
            for (int r = 0; r < 4; ++r)
                psum[m][r] += __shfl_xor(psum[m][r], off);
    if (lr == 0) {
        #pragma unroll
        for (int m = 0; m < 4; ++m)
            #pragma unroll
            for (int r = 0; r < 4; ++r)
                red[w][m * 16 + lg * 4 + r] = psum[m][r];
    }
    __syncthreads();
    if (tid < 64)
        lpart[(size_t)(i0 + tid) * TL + t] = red[0][tid] + red[1][tid] + red[2][tid] + red[3][tid];
}

__global__ __launch_bounds__(256, 4) void k_pv3(
    const unsigned short* __restrict__ qg, const unsigned short* __restrict__ kg,
    const unsigned short* __restrict__ xt, const float* __restrict__ linv,
    const float* __restrict__ x, float* __restrict__ out)
{
    __shared__ unsigned short P[32 * 64];
    const int tid = threadIdx.x, lane = tid & 63, w = tid >> 6;
    const int lr = lane & 15, lg = lane >> 4;
    const int bid = blockIdx.x;
    const int lid = (bid & 7) * (4608 / 8) + (bid >> 3);
    const int it = lid % 12, t = lid / 12;
    const int i0 = it * 32;
    const int h0 = blockIdx.y * 256 + w * 64;

    bf16x8 aq[2][4];
    #pragma unroll
    for (int m = 0; m < 2; ++m) {
        const unsigned short* qp = qg + ((size_t)t * NT + i0 + m * 16 + lr) * DD + lg * 8;
        #pragma unroll
        for (int kk = 0; kk < 4; ++kk) aq[m][kk] = *(const bf16x8*)(qp + kk * 32);
    }
    f32x4 acc[2][4];
    #pragma unroll
    for (int m = 0; m < 2; ++m)
        #pragma unroll
        for (int n = 0; n < 4; ++n) acc[m][n] = (f32x4){0.f, 0.f, 0.f, 0.f};

    const int nch = (i0 + 32 + 63) >> 6;
    for (int c = 0; c < nch; ++c) {
        const int j0 = c * 64;
        __syncthreads();
        f32x4 s[2] = { (f32x4){0,0,0,0}, (f32x4){0,0,0,0} };
        const unsigned short* kp = kg + ((size_t)t * NT + j0 + w * 16 + lr) * DD + lg * 8;
        #pragma unroll
        for (int kk = 0; kk < 4; ++kk) {
            const bf16x8 bk8 = *(const bf16x8*)(kp + kk * 32);
            s[0] = __builtin_amdgcn_mfma_f32_16x16x32_bf16(aq[0][kk], bk8, s[0], 0, 0, 0);
            s[1] = __builtin_amdgcn_mfma_f32_16x16x32_bf16(aq[1][kk], bk8, s[1], 0, 0, 0);
        }
        const int jg = j0 + w * 16 + lr;
        const int jl = w * 16 + lr;
        #pragma unroll
        for (int m = 0; m < 2; ++m)
            #pragma unroll
            for (int r = 0; r < 4; ++r) {
                const int il = m * 16 + lg * 4 + r;
                const float wv = (jg <= i0 + il) ? __expf(s[m][r]) : 0.f;
                P[il * 64 + (((jl >> 3) ^ (il & 7)) * 8) + (jl & 7)] = f2b(wv);
            }
        __syncthreads();
        #pragma unroll
        for (int kk2 = 0; kk2 < 2; ++kk2) {
            bf16x8 pa[2];
            #pragma unroll
            for (int m = 0; m < 2; ++m) {
                const int il = m * 16 + lr;
                const int ch = kk2 * 4 + lg;
                pa[m] = *(const bf16x8*)&P[il * 64 + ((ch ^ (il & 7)) * 8)];
            }
            const unsigned short* xp =
                xt + (((size_t)t * 12 + (j0 >> 5) + kk2) * HD + h0 + lr) * 32 + lg * 8;
            #pragma unroll
            for (int n = 0; n < 4; ++n) {
                const bf16x8 bx = *(const bf16x8*)(xp + n * 512);
                acc[0][n] = __builtin_amdgcn_mfma_f32_16x16x32_bf16(pa[0], bx, acc[0][n], 0, 0, 0);
                acc[1][n] = __builtin_amdgcn_mfma_f32_16x16x32_bf16(pa[1], bx, acc[1][n], 0, 0, 0);
            }
        }
    }
    #pragma unroll
    for (int m = 0; m < 2; ++m)
        #pragma unroll
        for (int r = 0; r < 4; ++r) {
            const int gi = i0 + m * 16 + lg * 4 + r;
            float* op = out + ((size_t)gi * TL + t) * HD + h0 + lr;
            if (gi == 0) {
                const float* xp0 = x + (size_t)t * HD + h0 + lr;
                #pragma unroll
                for (int n = 0; n < 4; ++n) op[n * 16] = xp0[n * 16];
            } else {
                const float sc = linv[gi];
                #pragma unroll
                for (int n = 0; n < 4; ++n) op[n * 16] = acc[m][n][r] * sc;
            }
        }
}

extern "C" void kernel_launch(void* const* d_in, const int* in_sizes, int n_in,
                              void* d_out, int out_size, void* d_ws, size_t ws_size,
                              hipStream_t stream)
{
    const float* x  = (const float*)d_in[0];
    const float* Wq = (const float*)d_in[1];
    const float* bq = (const float*)d_in[2];
    const float* Wk = (const float*)d_in[3];
    const float* bk = (const float*)d_in[4];
    float* out = (float*)d_out;

    unsigned short* Wt = (unsigned short*)d_ws;                 // 256*768 bf16
    unsigned short* qb = Wt + (size_t)256 * HD;                 // NT*TL*DD bf16
    unsigned short* kb = qb + (size_t)NT * TL * DD;             // NT*TL*DD bf16
    float* lpart = (float*)(kb + (size_t)NT * TL * DD);         // NT*TL f32
    float* linv  = lpart + (size_t)NT * TL;                     // NT f32
    unsigned short* xt = (unsigned short*)(linv + NT);          // TL*12*HD*32 bf16
    unsigned short* Pt = xt + (size_t)TL * 12 * HD * 32;        // TL*PT_T bf16

    const size_t need = (size_t)((char*)(Pt + (size_t)TL * PT_T) - (char*)d_ws);
    const bool use_split = ws_size >= need;

    kw_prep<<<dim3(768), 256, 0, stream>>>(Wq, Wk, Wt);
    k_proj<<<dim3(NT * TL / 64), 256, 0, stream>>>(x, Wt, bq, bk, qb, kb);
    k_xt<<<dim3(36, TL), 256, 0, stream>>>(x, xt);
    if (use_split) {
        k_qk<<<dim3(2304), 256, 0, stream>>>(qb, kb, Pt, lpart);
        k_lred<<<dim3(NT), 256, 0, stream>>>(lpart, linv);
        k_pv_g<<<dim3(13824), 256, 0, stream>>>(Pt, xt, linv, x, out);
    } else {
        k_stats64<<<dim3(2304), 256, 0, stream>>>(qb, kb, lpart);
        k_lred<<<dim3(NT), 256, 0, stream>>>(lpart, linv);
        k_pv3<<<dim3(4608, 3), 256, 0, stream>>>(qb, kb, xt, linv, x, out);
    }
}

// Round 9
// 707.712 us; speedup vs baseline: 1.0316x; 1.0316x over previous
//
#include <hip/hip_runtime.h>
#include <hip/hip_bf16.h>
#include <math.h>

#define NT 384   // turns
#define TL 384   // per-turn seq len
#define HD 768   // hidden
#define DD 128   // qk proj dim
#define PT_T 86016          // packed P elems per t: 64*64*Sum_{it<6}(it+1)
// packed P layout per t: tile it64 at 2048*it64*(it64+1); chunk32 jc at +jc*2048;
// elem (i_local 0..63, jo 0..31): + i_local*32 + jo.

typedef __attribute__((ext_vector_type(8))) short bf16x8;
typedef __attribute__((ext_vector_type(8))) unsigned short u16x8;
typedef __attribute__((ext_vector_type(4))) float f32x4;

__device__ __forceinline__ unsigned short f2b(float f) {
    union { float f; unsigned int u; } v; v.f = f;
    unsigned int r = v.u + 0x7FFFu + ((v.u >> 16) & 1u);   // RNE
    return (unsigned short)(r >> 16);
}

// ---------------------------------------------------------------------------
// kw_prep: Wt[n][k] = bf16(n<128 ? Wq[k][n] : Wk[k][n-128]); [256][768]
// ---------------------------------------------------------------------------
__global__ __launch_bounds__(256) void kw_prep(
    const float* __restrict__ Wq, const float* __restrict__ Wk,
    unsigned short* __restrict__ Wt)
{
    const int idx = blockIdx.x * 256 + threadIdx.x;     // 0 .. 196607
    const int k = idx >> 8, n = idx & 255;
    const float v = (n < DD) ? Wq[(size_t)k * DD + n] : Wk[(size_t)k * DD + (n - DD)];
    Wt[(size_t)n * HD + k] = f2b(v);
}

// ---------------------------------------------------------------------------
// k_proj: MFMA GEMM  C[147456][256] = x[147456][768] @ (Wq|Wk)[768][256]
// Outputs in [t][row][d] layout: qg/kg[((t*NT)+i)*DD + d].
// ---------------------------------------------------------------------------
__global__ __launch_bounds__(256, 3) void k_proj(
    const float* __restrict__ x, const unsigned short* __restrict__ Wt,
    const float* __restrict__ bq, const float* __restrict__ bk,
    unsigned short* __restrict__ qg, unsigned short* __restrict__ kg)
{
    __shared__ unsigned short As[64 * 64];   // [m][k] bf16, 16B-chunk XOR swizzle
    const int tid = threadIdx.x;
    const int lane = tid & 63;
    const int w = tid >> 6;
    const int row0 = blockIdx.x * 64;
    const int n0w = w * 64;
    const int lr = lane & 15;
    const int lg = lane >> 4;

    f32x4 acc[4][4];
    #pragma unroll
    for (int m = 0; m < 4; ++m)
        #pragma unroll
        for (int n = 0; n < 4; ++n) acc[m][n] = (f32x4){0.f, 0.f, 0.f, 0.f};

    const int sm = tid >> 2;           // staging row 0..63
    const int sc0 = (tid & 3) * 2;     // staging 16B-chunk pair

    for (int k0 = 0; k0 < HD; k0 += 64) {
        __syncthreads();
        {   // stage A tile [64 m][64 k] as bf16, swizzled
            const float* xp = x + (size_t)(row0 + sm) * HD + k0 + (tid & 3) * 16;
            u16x8 v0, v1;
            #pragma unroll
            for (int u4 = 0; u4 < 2; ++u4) {
                float4 f = *(const float4*)(xp + u4 * 4);
                v0[u4*4+0] = f2b(f.x); v0[u4*4+1] = f2b(f.y);
                v0[u4*4+2] = f2b(f.z); v0[u4*4+3] = f2b(f.w);
            }
            #pragma unroll
            for (int u4 = 0; u4 < 2; ++u4) {
                float4 f = *(const float4*)(xp + 8 + u4 * 4);
                v1[u4*4+0] = f2b(f.x); v1[u4*4+1] = f2b(f.y);
                v1[u4*4+2] = f2b(f.z); v1[u4*4+3] = f2b(f.w);
            }
            *(u16x8*)&As[sm * 64 + ((sc0     ^ (sm & 7)) * 8)] = v0;
            *(u16x8*)&As[sm * 64 + (((sc0+1) ^ (sm & 7)) * 8)] = v1;
        }
        __syncthreads();
        #pragma unroll
        for (int kk = 0; kk < 2; ++kk) {
            bf16x8 a[4], b[4];
            #pragma unroll
            for (int m = 0; m < 4; ++m) {
                const int mi = m * 16 + lr;
                const int phys = (lg + kk * 4) ^ (mi & 7);
                a[m] = *(const bf16x8*)&As[mi * 64 + phys * 8];
            }
            #pragma unroll
            for (int n = 0; n < 4; ++n) {
                const int ncol = n0w + n * 16 + lr;
                b[n] = *(const bf16x8*)(Wt + (size_t)ncol * HD + k0 + kk * 32 + lg * 8);
            }
            #pragma unroll
            for (int m = 0; m < 4; ++m)
                #pragma unroll
                for (int n = 0; n < 4; ++n)
                    acc[m][n] = __builtin_amdgcn_mfma_f32_16x16x32_bf16(a[m], b[n], acc[m][n], 0, 0, 0);
        }
    }
    const float scale = 0.08838834764831845f;   // 1/sqrt(128), folded into q
    const int ib = row0 / TL;                   // turn index (constant per block)
    const int tb = row0 % TL;                   // base t within turn
    #pragma unroll
    for (int n = 0; n < 4; ++n) {
        const int ncol = n0w + n * 16 + lr;
        const bool isq = ncol < DD;
        const int d = isq ? ncol : ncol - DD;
        const float bias = isq ? bq[d] : bk[d];
        unsigned short* dst = isq ? qg : kg;
        #pragma unroll
        for (int m = 0; m < 4; ++m)
            #pragma unroll
            for (int r = 0; r < 4; ++r) {
                const int t = tb + m * 16 + lg * 4 + r;
                float v = acc[m][n][r] + bias;
                if (isq) v *= scale;
                dst[((size_t)t * NT + ib) * DD + d] = f2b(v);
            }
    }
}

// ---------------------------------------------------------------------------
// k_xt: xt5[t][j/32][h][j%32] = bf16(x[j][t][h]). Coalesced-write remap:
// thread = (joblk = tid&3, h_local = tid>>2); owns 8 j x 4 h. Each u16x8
// store covers jo joblk*8..+8 at fixed h -> a wave fills full 64B sectors.
// grid: (36 = jc*3+hb, 384 t).
// ---------------------------------------------------------------------------
__global__ __launch_bounds__(256, 4) void k_xt(
    const float* __restrict__ x, unsigned short* __restrict__ xt)
{
    const int tid = threadIdx.x;
    const int hb = blockIdx.x % 3;          // h-tile of 256
    const int jc = blockIdx.x / 3;          // j-chunk of 32
    const int t  = blockIdx.y;
    const int joblk   = tid & 3;            // jo base = joblk*8
    const int h_local = tid >> 2;           // 0..63 -> h = hb*256 + h_local*4
    const int hbase = hb * 256 + h_local * 4;

    float4 v[8];
    #pragma unroll
    for (int r = 0; r < 8; ++r) {
        const int j = jc * 32 + joblk * 8 + r;
        v[r] = *(const float4*)&x[((size_t)j * TL + t) * HD + hbase];
    }
    #pragma unroll
    for (int e = 0; e < 4; ++e) {
        u16x8 w;
        w[0] = f2b(v[0][e]); w[1] = f2b(v[1][e]);
        w[2] = f2b(v[2][e]); w[3] = f2b(v[3][e]);
        w[4] = f2b(v[4][e]); w[5] = f2b(v[5][e]);
        w[6] = f2b(v[6][e]); w[7] = f2b(v[7][e]);
        *(u16x8*)&xt[(((size_t)t * 12 + jc) * HD + hbase + e) * 32 + joblk * 8] = w;
    }
}

// ---------------------------------------------------------------------------
// k_qk: i-tile 64, 256 threads (4 waves). Per 64-j chunk: wave w owns
// j-slice w*16, computes S for all 4 m-tiles (16 MFMA / 4 loads),
// P = mask?exp(s):0 -> packed burst-layout Pt (bf16) + row-sum partials.
// ---------------------------------------------------------------------------
__global__ __launch_bounds__(256, 4) void k_qk(
    const unsigned short* __restrict__ qg, const unsigned short* __restrict__ kg,
    unsigned short* __restrict__ Pt, float* __restrict__ lpart)
{
    __shared__ float red[4][64];
    const int tid = threadIdx.x, lane = tid & 63, w = tid >> 6;
    const int lr = lane & 15, lg = lane >> 4;
    const int bid = blockIdx.x;
    const int lid = (bid & 7) * (2304 / 8) + (bid >> 3);   // XCD-chunk swizzle
    const int it = lid % 6, t = lid / 6;
    const int i0 = it * 64;
    unsigned short* ptile = Pt + (size_t)t * PT_T + 2048 * (size_t)(it * (it + 1));

    bf16x8 aq[4][4];
    #pragma unroll
    for (int m = 0; m < 4; ++m) {
        const unsigned short* qp = qg + ((size_t)t * NT + i0 + m * 16 + lr) * DD + lg * 8;
        #pragma unroll
        for (int kk = 0; kk < 4; ++kk) aq[m][kk] = *(const bf16x8*)(qp + kk * 32);
    }
    float psum[4][4];
    #pragma unroll
    for (int m = 0; m < 4; ++m)
        #pragma unroll
        for (int r = 0; r < 4; ++r) psum[m][r] = 0.f;

    for (int c = 0; c <= it; ++c) {
        const int j0 = c * 64;
        const unsigned short* kp = kg + ((size_t)t * NT + j0 + w * 16 + lr) * DD + lg * 8;
        bf16x8 bk8[4];
        #pragma unroll
        for (int kk = 0; kk < 4; ++kk) bk8[kk] = *(const bf16x8*)(kp + kk * 32);
        const int jg = j0 + w * 16 + lr;
        unsigned short* pst = ptile + (size_t)(c * 2 + (w >> 1)) * 2048 + (w & 1) * 16 + lr;
        #pragma unroll
        for (int m = 0; m < 4; ++m) {
            f32x4 s = (f32x4){0.f, 0.f, 0.f, 0.f};
            #pragma unroll
            for (int kk = 0; kk < 4; ++kk)
                s = __builtin_amdgcn_mfma_f32_16x16x32_bf16(aq[m][kk], bk8[kk], s, 0, 0, 0);
            #pragma unroll
            for (int r = 0; r < 4; ++r) {
                const int il = m * 16 + lg * 4 + r;
                const float wv = (jg <= i0 + il) ? __expf(s[r]) : 0.f;
                psum[m][r] += wv;
                pst[il * 32] = f2b(wv);
            }
        }
    }
    #pragma unroll
    for (int off = 1; off < 16; off <<= 1)
        #pragma unroll
        for (int m = 0; m < 4; ++m)
            #pragma unroll
            for (int r = 0; r < 4; ++r)
                psum[m][r] += __shfl_xor(psum[m][r], off);
    if (lr == 0) {
        #pragma unroll
        for (int m = 0; m < 4; ++m)
            #pragma unroll
            for (int r = 0; r < 4; ++r)
                red[w][m * 16 + lg * 4 + r] = psum[m][r];
    }
    __syncthreads();
    if (tid < 64)
        lpart[(size_t)(i0 + tid) * TL + t] = red[0][tid] + red[1][tid] + red[2][tid] + red[3][tid];
}

// ---------------------------------------------------------------------------
// k_lred: linv[i] = 1 / sum_t lpart[i][t]
// ---------------------------------------------------------------------------
__global__ __launch_bounds__(256) void k_lred(const float* __restrict__ lpart,
                                              float* __restrict__ linv)
{
    const int i = blockIdx.x;
    const int tid = threadIdx.x;
    float s = 0.f;
    for (int t = tid; t < TL; t += 256) s += lpart[(size_t)i * TL + t];
    #pragma unroll
    for (int off = 32; off >= 1; off >>= 1) s += __shfl_down(s, off);
    __shared__ float red[4];
    if ((tid & 63) == 0) red[tid >> 6] = s;
    __syncthreads();
    if (tid == 0) linv[i] = 1.f / (red[0] + red[1] + red[2] + red[3]);
}

// ---------------------------------------------------------------------------
// k_pv_g: pure GEMM, no LDS/barriers/exp. Block = (t, i-tile 32, h-256);
// 4 waves x h-64. 2-deep software pipeline: chunk c+1's 6 loads issue
// BEFORE chunk c's MFMAs (statically double-buffered A/B frag sets), so
// the compiler emits counted vmcnt and L2 latency hides under compute.
// Epilogue: out = acc*linv[i]; row-0 fp32 passthrough folded in.
// ---------------------------------------------------------------------------
__global__ __launch_bounds__(256, 5) void k_pv_g(
    const unsigned short* __restrict__ Pt, const unsigned short* __restrict__ xt,
    const float* __restrict__ linv, const float* __restrict__ x,
    float* __restrict__ out)
{
    const int tid = threadIdx.x, lane = tid & 63, w = tid >> 6;
    const int lr = lane & 15, lg = lane >> 4;
    const int bid = blockIdx.x;             // 0 .. 13823
    const int lid = (bid & 7) * (13824 / 8) + (bid >> 3);
    const int hb  = lid % 3;
    const int rem = lid / 3;                // 0 .. 4607, t-contiguous per XCD
    const int it32 = rem % 12, t = rem / 12;
    const int i0 = it32 * 32;
    const int h0 = hb * 256 + w * 64;
    const int it64 = it32 >> 1;
    const int rowhalf = (it32 & 1) * 32;

    const unsigned short* pbase = Pt + (size_t)t * PT_T + 2048 * (size_t)(it64 * (it64 + 1))
                                + (size_t)(rowhalf + lr) * 32 + lg * 8;
    const unsigned short* xbase = xt + (((size_t)t * 12) * HD + h0 + lr) * 32 + lg * 8;

    f32x4 acc[2][4];
    #pragma unroll
    for (int m = 0; m < 2; ++m)
        #pragma unroll
        for (int n = 0; n < 4; ++n) acc[m][n] = (f32x4){0.f, 0.f, 0.f, 0.f};

    bf16x8 paA0, paA1, bxA0, bxA1, bxA2, bxA3;
    bf16x8 paB0, paB1, bxB0, bxB1, bxB2, bxB3;

#define LOADSET(P0, P1, B0, B1, B2, B3, cc) do {                               \
        const unsigned short* pp_ = pbase + (size_t)(cc) * 2048;               \
        P0 = *(const bf16x8*)(pp_);                                            \
        P1 = *(const bf16x8*)(pp_ + 512);                                      \
        const unsigned short* xp_ = xbase + (size_t)(cc) * (HD * 32);          \
        B0 = *(const bf16x8*)(xp_);                                            \
        B1 = *(const bf16x8*)(xp_ + 512);                                      \
        B2 = *(const bf16x8*)(xp_ + 1024);                                     \
        B3 = *(const bf16x8*)(xp_ + 1536);                                     \
    } while (0)

#define MFMASET(P0, P1, B0, B1, B2, B3) do {                                   \
        acc[0][0] = __builtin_amdgcn_mfma_f32_16x16x32_bf16(P0, B0, acc[0][0], 0, 0, 0); \
        acc[1][0] = __builtin_amdgcn_mfma_f32_16x16x32_bf16(P1, B0, acc[1][0], 0, 0, 0); \
        acc[0][1] = __builtin_amdgcn_mfma_f32_16x16x32_bf16(P0, B1, acc[0][1], 0, 0, 0); \
        acc[1][1] = __builtin_amdgcn_mfma_f32_16x16x32_bf16(P1, B1, acc[1][1], 0, 0, 0); \
        acc[0][2] = __builtin_amdgcn_mfma_f32_16x16x32_bf16(P0, B2, acc[0][2], 0, 0, 0); \
        acc[1][2] = __builtin_amdgcn_mfma_f32_16x16x32_bf16(P1, B2, acc[1][2], 0, 0, 0); \
        acc[0][3] = __builtin_amdgcn_mfma_f32_16x16x32_bf16(P0, B3, acc[0][3], 0, 0, 0); \
        acc[1][3] = __builtin_amdgcn_mfma_f32_16x16x32_bf16(P1, B3, acc[1][3], 0, 0, 0); \
    } while (0)

    const int nq = it32 + 1;
    LOADSET(paA0, paA1, bxA0, bxA1, bxA2, bxA3, 0);
    int c = 0;
    while (c + 1 < nq) {
        LOADSET(paB0, paB1, bxB0, bxB1, bxB2, bxB3, c + 1);
        MFMASET(paA0, paA1, bxA0, bxA1, bxA2, bxA3);
        if (c + 2 < nq)
            LOADSET(paA0, paA1, bxA0, bxA1, bxA2, bxA3, c + 2);
        MFMASET(paB0, paB1, bxB0, bxB1, bxB2, bxB3);
        c += 2;
    }
    if (c < nq)
        MFMASET(paA0, paA1, bxA0, bxA1, bxA2, bxA3);
#undef LOADSET
#undef MFMASET

    // ---- epilogue: normalize + single write; row-0 fp32 passthrough ----
    #pragma unroll
    for (int m = 0; m < 2; ++m)
        #pragma unroll
        for (int r = 0; r < 4; ++r) {
            const int gi = i0 + m * 16 + lg * 4 + r;
            float* op = out + ((size_t)gi * TL + t) * HD + h0 + lr;
            if (gi == 0) {
                const float* xp0 = x + (size_t)t * HD + h0 + lr;
                #pragma unroll
                for (int n = 0; n < 4; ++n) op[n * 16] = xp0[n * 16];
            } else {
                const float sc = linv[gi];
                #pragma unroll
                for (int n = 0; n < 4; ++n) op[n * 16] = acc[m][n][r] * sc;
            }
        }
}

// ---------------------------------------------------------------------------
// Fallback path (proven round-6): k_stats64 + k_pv3, used if ws too small.
// ---------------------------------------------------------------------------
__global__ __launch_bounds__(256, 4) void k_stats64(
    const unsigned short* __restrict__ qg, const unsigned short* __restrict__ kg,
    float* __restrict__ lpart)
{
    __shared__ float red[4][64];
    const int tid = threadIdx.x, lane = tid & 63, w = tid >> 6;
    const int lr = lane & 15, lg = lane >> 4;
    const int bid = blockIdx.x;
    const int lid = (bid & 7) * (2304 / 8) + (bid >> 3);
    const int it = lid % 6, t = lid / 6;
    const int i0 = it * 64;

    bf16x8 aq[4][4];
    #pragma unroll
    for (int m = 0; m < 4; ++m) {
        const unsigned short* qp = qg + ((size_t)t * NT + i0 + m * 16 + lr) * DD + lg * 8;
        #pragma unroll
        for (int kk = 0; kk < 4; ++kk) aq[m][kk] = *(const bf16x8*)(qp + kk * 32);
    }
    float psum[4][4];
    #pragma unroll
    for (int m = 0; m < 4; ++m)
        #pragma unroll
        for (int r = 0; r < 4; ++r) psum[m][r] = 0.f;

    for (int c = 0; c <= it; ++c) {
        const int j0 = c * 64;
        const unsigned short* kp = kg + ((size_t)t * NT + j0 + w * 16 + lr) * DD + lg * 8;
        bf16x8 bk8[4];
        #pragma unroll
        for (int kk = 0; kk < 4; ++kk) bk8[kk] = *(const bf16x8*)(kp + kk * 32);
        const int jg = j0 + w * 16 + lr;
        #pragma unroll
        for (int m = 0; m < 4; ++m) {
            f32x4 s = (f32x4){0.f, 0.f, 0.f, 0.f};
            #pragma unroll
            for (int kk = 0; kk < 4; ++kk)
                s = __builtin_amdgcn_mfma_f32_16x16x32_bf16(aq[m][kk], bk8[kk], s, 0, 0, 0);
            #pragma unroll
            for (int r = 0; r < 4; ++r) {
                const int ig = i0 + m * 16 + lg * 4 + r;
                psum[m][r] += (jg <= ig) ? __expf(s[r]) : 0.f;
            }
        }
    }
    #pragma unroll
    for (int off = 1; off < 16; off <<= 1)
        #pragma unroll
        for (int m = 0; m < 4; ++m)
            #pragma unroll
            for (int r = 0; r < 4; ++r)
                psum[m][r] += __shfl_xor(psum[m][r], off);
    if (lr == 0) {
        #pragma unroll
        for (int m = 0; m < 4; ++m)
            #pragma unroll
            for (int r = 0; r < 4; ++r)
                red[w][m * 16 + lg * 4 + r] = psum[m][r];
    }
    __syncthreads();
    if (tid < 64)
        lpart[(size_t)(i0 + tid) * TL + t] = red[0][tid] + red[1][tid] + red[2][tid] + red[3][tid];
}

__global__ __launch_bounds__(256, 4) void k_pv3(
    const unsigned short* __restrict__ qg, const unsigned short* __restrict__ kg,
    const unsigned short* __restrict__ xt, const float* __restrict__ linv,
    const float* __restrict__ x, float* __restrict__ out)
{
    __shared__ unsigned short P[32 * 64];
    const int tid = threadIdx.x, lane = tid & 63, w = tid >> 6;
    const int lr = lane & 15, lg = lane >> 4;
    const int bid = blockIdx.x;
    const int lid = (bid & 7) * (4608 / 8) + (bid >> 3);
    const int it = lid % 12, t = lid / 12;
    const int i0 = it * 32;
    const int h0 = blockIdx.y * 256 + w * 64;

    bf16x8 aq[2][4];
    #pragma unroll
    for (int m = 0; m < 2; ++m) {
        const unsigned short* qp = qg + ((size_t)t * NT + i0 + m * 16 + lr) * DD + lg * 8;
        #pragma unroll
        for (int kk = 0; kk < 4; ++kk) aq[m][kk] = *(const bf16x8*)(qp + kk * 32);
    }
    f32x4 acc[2][4];
    #pragma unroll
    for (int m = 0; m < 2; ++m)
        #pragma unroll
        for (int n = 0; n < 4; ++n) acc[m][n] = (f32x4){0.f, 0.f, 0.f, 0.f};

    const int nch = (i0 + 32 + 63) >> 6;
    for (int c = 0; c < nch; ++c) {
        const int j0 = c * 64;
        __syncthreads();
        f32x4 s[2] = { (f32x4){0,0,0,0}, (f32x4){0,0,0,0} };
        const unsigned short* kp = kg + ((size_t)t * NT + j0 + w * 16 + lr) * DD + lg * 8;
        #pragma unroll
        for (int kk = 0; kk < 4; ++kk) {
            const bf16x8 bk8 = *(const bf16x8*)(kp + kk * 32);
            s[0] = __builtin_amdgcn_mfma_f32_16x16x32_bf16(aq[0][kk], bk8, s[0], 0, 0, 0);
            s[1] = __builtin_amdgcn_mfma_f32_16x16x32_bf16(aq[1][kk], bk8, s[1], 0, 0, 0);
        }
        const int jg = j0 + w * 16 + lr;
        const int jl = w * 16 + lr;
        #pragma unroll
        for (int m = 0; m < 2; ++m)
            #pragma unroll
            for (int r = 0; r < 4; ++r) {
                const int il = m * 16 + lg * 4 + r;
                const float wv = (jg <= i0 + il) ? __expf(s[m][r]) : 0.f;
                P[il * 64 + (((jl >> 3) ^ (il & 7)) * 8) + (jl & 7)] = f2b(wv);
            }
        __syncthreads();
        #pragma unroll
        for (int kk2 = 0; kk2 < 2; ++kk2) {
            bf16x8 pa[2];
            #pragma unroll
            for (int m = 0; m < 2; ++m) {
                const int il = m * 16 + lr;
                const int ch = kk2 * 4 + lg;
                pa[m] = *(const bf16x8*)&P[il * 64 + ((ch ^ (il & 7)) * 8)];
            }
            const unsigned short* xp =
                xt + (((size_t)t * 12 + (j0 >> 5) + kk2) * HD + h0 + lr) * 32 + lg * 8;
            #pragma unroll
            for (int n = 0; n < 4; ++n) {
                const bf16x8 bx = *(const bf16x8*)(xp + n * 512);
                acc[0][n] = __builtin_amdgcn_mfma_f32_16x16x32_bf16(pa[0], bx, acc[0][n], 0, 0, 0);
                acc[1][n] = __builtin_amdgcn_mfma_f32_16x16x32_bf16(pa[1], bx, acc[1][n], 0, 0, 0);
            }
        }
    }
    #pragma unroll
    for (int m = 0; m < 2; ++m)
        #pragma unroll
        for (int r = 0; r < 4; ++r) {
            const int gi = i0 + m * 16 + lg * 4 + r;
            float* op = out + ((size_t)gi * TL + t) * HD + h0 + lr;
            if (gi == 0) {
                const float* xp0 = x + (size_t)t * HD + h0 + lr;
                #pragma unroll
                for (int n = 0; n < 4; ++n) op[n * 16] = xp0[n * 16];
            } else {
                const float sc = linv[gi];
                #pragma unroll
                for (int n = 0; n < 4; ++n) op[n * 16] = acc[m][n][r] * sc;
            }
        }
}

extern "C" void kernel_launch(void* const* d_in, const int* in_sizes, int n_in,
                              void* d_out, int out_size, void* d_ws, size_t ws_size,
                              hipStream_t stream)
{
    const float* x  = (const float*)d_in[0];
    const float* Wq = (const float*)d_in[1];
    const float* bq = (const float*)d_in[2];
    const float* Wk = (const float*)d_in[3];
    const float* bk = (const float*)d_in[4];
    float* out = (float*)d_out;

    unsigned short* Wt = (unsigned short*)d_ws;                 // 256*768 bf16
    unsigned short* qb = Wt + (size_t)256 * HD;                 // NT*TL*DD bf16
    unsigned short* kb = qb + (size_t)NT * TL * DD;             // NT*TL*DD bf16
    float* lpart = (float*)(kb + (size_t)NT * TL * DD);         // NT*TL f32
    float* linv  = lpart + (size_t)NT * TL;                     // NT f32
    unsigned short* xt = (unsigned short*)(linv + NT);          // TL*12*HD*32 bf16
    unsigned short* Pt = xt + (size_t)TL * 12 * HD * 32;        // TL*PT_T bf16

    const size_t need = (size_t)((char*)(Pt + (size_t)TL * PT_T) - (char*)d_ws);
    const bool use_split = ws_size >= need;

    kw_prep<<<dim3(768), 256, 0, stream>>>(Wq, Wk, Wt);
    k_proj<<<dim3(NT * TL / 64), 256, 0, stream>>>(x, Wt, bq, bk, qb, kb);
    k_xt<<<dim3(36, TL), 256, 0, stream>>>(x, xt);
    if (use_split) {
        k_qk<<<dim3(2304), 256, 0, stream>>>(qb, kb, Pt, lpart);
        k_lred<<<dim3(NT), 256, 0, stream>>>(lpart, linv);
        k_pv_g<<<dim3(13824), 256, 0, stream>>>(Pt, xt, linv, x, out);
    } else {
        k_stats64<<<dim3(2304), 256, 0, stream>>>(qb, kb, lpart);
        k_lred<<<dim3(NT), 256, 0, stream>>>(lpart, linv);
        k_pv3<<<dim3(4608, 3), 256, 0, stream>>>(qb, kb, xt, linv, x, out);
    }
}